// Round 12
// baseline (351.813 us; speedup 1.0000x reference)
//
#include <hip/hip_runtime.h>
#include <math.h>

#define NBATCH 32
#define S      49152
#define NF     24          // frames (2048 samples each)
#define NB     16          // biquads
#define NBLK   4           // blocks per batch (R9-proven best)
#define CHUNK  16          // samples per thread (R9-proven; 32 spills)
#define NCH    768         // threads per block
#define NWAVE  12          // waves per block
// R20 = R16 (best clean, 71.5us) with the second level DISTRIBUTED to every
// wave. Evidence R18/R19: the +8us in both was the fused STEPF loop (the only
// common change); DPP-vs-shfl was null -> KS latency is TLP-hidden; R16's
// -3.5us showed matrix algebra wasn't the cost. Remaining serial segment:
// the flag chain (wave0 fold -> poll -> sv write -> sflag release -> 11 waves
// spin -> sv LDS read). R20 removes it: post-barrier, EVERY wave folds its
// own exclusive-prefix constant from sagg (<=11 x 6 fma, precomputed sMw),
// polls the <=3 pred-quarter slots itself (wave-uniform spin, lane-redundant
// loads, precomputed sWm fold -- no shfl), wave 11 composes block-inclusive
// and publishes. No sv, no sflag, one barrier per round, symmetric waves.
// ce shfl issues pre-barrier (latency hides under convergence).
// [R20b: resubmit verbatim -- R20 bench was an infra failure (container
// acquire failed twice), not a kernel verdict. Deadlock/dbuf/stale-tag
// audit passed: publishes parallel & acyclic, sagg dbuf race-free under
// one-barrier pipelining, ws reset between iterations by harness.]
// Health: WRITE ~7MB, VGPR <= ~72, absmax 0.015625.

__device__ __forceinline__ float clampf(float x, float lo, float hi) {
    return fminf(fmaxf(x, lo), hi);
}

// 16 named scalar signal registers (SSA-guaranteed; arrays spill).
#define FOREACH_S(OP) \
    OP(s00) OP(s01) OP(s02) OP(s03) OP(s04) OP(s05) OP(s06) OP(s07) \
    OP(s08) OP(s09) OP(s10) OP(s11) OP(s12) OP(s13) OP(s14) OP(s15)

#define DECL_S(x) float x;

// Phase A step: state only.  s' = T s + b*x
#define STEPA(x) { \
    const float n1_ = fmaf(t00, ic1, fmaf(t01, ic2, b0 * (x))); \
    const float n2_ = fmaf(t10, ic1, fmaf(t11, ic2, b1 * (x))); \
    ic1 = n1_; ic2 = n2_; }

// Phase C step: output + state.  y = c0*ic1 + c1*ic2 + c2*x, in place.
#define STEPC(x) { \
    const float y_  = fmaf(c0, ic1, fmaf(c1, ic2, c2 * (x))); \
    const float n1_ = fmaf(t00, ic1, fmaf(t01, ic2, b0 * (x))); \
    const float n2_ = fmaf(t10, ic1, fmaf(t11, ic2, b1 * (x))); \
    (x) = y_; ic1 = n1_; ic2 = n2_; }

__global__ __launch_bounds__(NCH, 3)
void biquad_chain_kernel(const float* __restrict__ audio,
                         const float* __restrict__ params,
                         float* __restrict__ out,
                         unsigned int* __restrict__ ws)
{
    __shared__ __align__(16) float sc[NB][NF][16];  // affine(9) + T^16(4)
    __shared__ float4 sMw[NB][6];         // T^1024 per local frame
    __shared__ float4 sPm[NB][NWAVE];     // exclusive wave-prefix P_w
    __shared__ float4 sWm[NB][3];         // pred-quarter fold matrices W_k
    __shared__ float4 sT2048[NB][NF];     // frame aggregates (init/prefix only)
    __shared__ float  sgain[2][NF];       // [0]=in gain, [1]=out gain
    __shared__ float2 sagg[2][NWAVE];     // runtime wave constants (dbuf)

    const int t       = threadIdx.x;
    // XCD co-location swizzle: all 4 quarters of a batch on one XCD.
    const int xcd     = blockIdx.x & 7;
    const int slot_   = blockIdx.x >> 3;
    const int bt      = xcd * 4 + (slot_ & 3);   // batch
    const int quarter = slot_ >> 2;              // which quarter of the signal
    const int lane    = t & 63;
    const int wave    = t >> 6;
    const int frame   = quarter * 6 + (wave >> 1);  // 2 waves per 2048-frame

    // ---------------- coefficient init (threads 0..383) ----------------
    if (t < NB * NF) {
        const int f  = t / NF;
        const int fr = t % NF;
        const float* P = params + (size_t)bt * 50 * NF;
        const float fn = P[(3 * f + 0) * NF + fr];
        const float gn = P[(3 * f + 1) * NF + fr];
        const float qn = P[(3 * f + 2) * NF + fr];

        float Q = __expf(-0.69314718f + qn * 3.4657359f);
        Q = clampf(Q, 0.1f, 100.0f);

        float lo, hi;
        int type;                        // 0 hp, 1 lp, 2 peak, 3 lowshelf, 4 highshelf
        if      (f == 0)  { lo = 20.0f;   hi = 500.0f;   type = 0; }
        else if (f == 15) { lo = 5000.0f; hi = 20000.0f; type = 1; }
        else if (f == 1)  { lo = 50.0f;   hi = 16000.0f; type = 3; }
        else if (f == 14) { lo = 50.0f;   hi = 16000.0f; type = 4; }
        else              { lo = 100.0f;  hi = 15000.0f; type = 2; }

        const float fc = __expf(__logf(lo) + fn * (__logf(hi) - __logf(lo)));
        float g_ = __tanf((float)M_PI * fc / 96000.0f);   // angle <= 0.655 rad
        g_ = clampf(g_, 1e-6f, 100.0f);
        const float gdb = -24.0f + 48.0f * gn;

        float a1, a2, a3, m0, m1, m2;
        if (type == 0 || type == 1) {
            const float k = 1.0f / Q;
            a1 = 1.0f / (1.0f + g_ * (g_ + k)); a2 = g_ * a1; a3 = g_ * a2;
            if (type == 0) { m0 = 1.0f; m1 = -k;   m2 = -1.0f; }
            else           { m0 = 0.0f; m1 = 0.0f; m2 = 1.0f;  }
        } else if (type == 2) {
            const float A = __expf(gdb * (2.30258509f / 40.0f));
            const float k = (gdb >= 0.0f) ? 1.0f / (Q * A) : A / Q;
            a1 = 1.0f / (1.0f + g_ * (g_ + k)); a2 = g_ * a1; a3 = g_ * a2;
            m0 = 1.0f; m1 = k * (A * A - 1.0f); m2 = 0.0f;
        } else {
            const float A  = __expf(gdb * (2.30258509f / 40.0f));
            const float sA = sqrtf(A);
            const float k  = 1.0f / Q;
            float gs;
            if (type == 3) gs = (gdb >= 0.0f) ? g_ / sA : g_ * sA;
            else           gs = (gdb >= 0.0f) ? g_ * sA : g_ / sA;
            a1 = 1.0f / (1.0f + gs * (gs + k)); a2 = gs * a1; a3 = gs * a2;
            if (type == 3) { m0 = 1.0f;  m1 = k * (A - 1.0f);      m2 = A * A - 1.0f; }
            else           { m0 = A * A; m1 = k * (1.0f - A) * A;  m2 = 1.0f - A * A; }
        }

        // affine per-sample form: s' = T s + b*x ; y = c0*s1 + c1*s2 + c2*x
        const float q2  = a2 * a2 + a3;
        const float t00 = 2.0f * a1 - 1.0f;
        const float t01 = -2.0f * a2;
        const float t10 = 2.0f * a1 * a2;
        const float t11 = 1.0f - 2.0f * q2;
        const float b0  = 2.0f * a2;
        const float b1  = 2.0f * q2;
        const float c0  = a1 * (m1 + m2 * a2);
        const float c1  = m2 * (1.0f - q2) - m1 * a2;
        const float c2  = m0 + m1 * a2 + m2 * q2;

        // T^16 by 4 squarings
        float u00 = t00, u01 = t01, u10 = t10, u11 = t11;
        #pragma unroll
        for (int i = 0; i < 4; i++) {
            const float n00 = u00 * u00 + u01 * u10;
            const float n01 = u00 * u01 + u01 * u11;
            const float n10 = u10 * u00 + u11 * u10;
            const float n11 = u10 * u01 + u11 * u11;
            u00 = n00; u01 = n01; u10 = n10; u11 = n11;
        }
        sc[f][fr][0] = t00; sc[f][fr][1] = t01; sc[f][fr][2] = t10; sc[f][fr][3] = t11;
        sc[f][fr][4] = b0;  sc[f][fr][5] = b1;  sc[f][fr][6] = c0;  sc[f][fr][7] = c1;
        sc[f][fr][8] = c2;  sc[f][fr][9] = u00; sc[f][fr][10] = u01; sc[f][fr][11] = u10;
        sc[f][fr][12] = u11;

        // continue squaring: T^16 -> T^1024 (6 more squarings)
        #pragma unroll
        for (int i = 0; i < 6; i++) {
            const float n00 = u00 * u00 + u01 * u10;
            const float n01 = u00 * u01 + u01 * u11;
            const float n10 = u10 * u00 + u11 * u10;
            const float n11 = u10 * u01 + u11 * u11;
            u00 = n00; u01 = n01; u10 = n10; u11 = n11;
        }
        const int lfr = fr - quarter * 6;
        if (lfr >= 0 && lfr < 6) {
            sMw[f][lfr] = make_float4(u00, u01, u10, u11);
        }
        // one more squaring: T^2048 (frame aggregate, ALL frames)
        {
            const float n00 = u00 * u00 + u01 * u10;
            const float n01 = u00 * u01 + u01 * u11;
            const float n10 = u10 * u00 + u11 * u10;
            const float n11 = u10 * u01 + u11 * u11;
            sT2048[f][fr] = make_float4(n00, n01, n10, n11);
        }
    }
    if (t >= 384 && t < 384 + 2 * NF) {
        const int idx = t - 384;
        const int which = idx / NF;     // 0 = in gain (row 48), 1 = out gain (row 49)
        const int fr    = idx % NF;
        const float* P = params + (size_t)bt * 50 * NF;
        const float p  = P[(48 + which) * NF + fr];
        const float db = -60.0f + 60.0f * p;
        sgain[which][fr] = __expf(db * (2.30258509f / 20.0f));
    }
    __syncthreads();

    // ------- prefix assembly (threads 0..15, one per stage) -------
    if (t < NB) {
        const int f = t;
        // exclusive wave prefixes P_w over local frames (Q = running product)
        float q00 = 1.0f, q01 = 0.0f, q10 = 0.0f, q11 = 1.0f;
        #pragma unroll
        for (int k = 0; k < 6; k++) {
            sPm[f][2 * k] = make_float4(q00, q01, q10, q11);
            const float4 mw = sMw[f][k];
            sPm[f][2 * k + 1] = make_float4(
                mw.x * q00 + mw.y * q10, mw.x * q01 + mw.y * q11,
                mw.z * q00 + mw.w * q10, mw.z * q01 + mw.w * q11);
            const float4 g = sT2048[f][quarter * 6 + k];
            const float n00 = g.x * q00 + g.y * q10;
            const float n01 = g.x * q01 + g.y * q11;
            const float n10 = g.z * q00 + g.w * q10;
            const float n11 = g.z * q01 + g.w * q11;
            q00 = n00; q01 = n01; q10 = n10; q11 = n11;
        }
        // pred-quarter fold matrices: W_{q-1}=I ; W_k = W_{k+1} * B_{k+1}
        if (quarter > 0) {
            float r00 = 1.0f, r01 = 0.0f, r10 = 0.0f, r11 = 1.0f;
            for (int k = quarter - 1; k >= 0; k--) {
                sWm[f][k] = make_float4(r00, r01, r10, r11);
                if (k > 0) {
                    float b00 = 1.0f, b01 = 0.0f, b10 = 0.0f, b11 = 1.0f;
                    #pragma unroll
                    for (int m = 0; m < 6; m++) {
                        const float4 g = sT2048[f][6 * k + m];
                        const float n00 = g.x * b00 + g.y * b10;
                        const float n01 = g.x * b01 + g.y * b11;
                        const float n10 = g.z * b00 + g.w * b10;
                        const float n11 = g.z * b01 + g.w * b11;
                        b00 = n00; b01 = n01; b10 = n10; b11 = n11;
                    }
                    const float n00 = r00 * b00 + r01 * b10;
                    const float n01 = r00 * b01 + r01 * b11;
                    const float n10 = r10 * b00 + r11 * b10;
                    const float n11 = r10 * b01 + r11 * b11;
                    r00 = n00; r01 = n01; r10 = n10; r11 = n11;
                }
            }
        }
    }
    __syncthreads();

    // ---------------- load chunk (with input gain) ----------------
    FOREACH_S(DECL_S)
    {
        const float ing = sgain[0][frame];
        const float* base = audio + (size_t)bt * S
                          + (size_t)(quarter * NCH + t) * CHUNK;
        float4 q;
        q = *(const float4*)(base +  0); s00 = q.x*ing; s01 = q.y*ing; s02 = q.z*ing; s03 = q.w*ing;
        q = *(const float4*)(base +  4); s04 = q.x*ing; s05 = q.y*ing; s06 = q.z*ing; s07 = q.w*ing;
        q = *(const float4*)(base +  8); s08 = q.x*ing; s09 = q.y*ing; s10 = q.z*ing; s11 = q.w*ing;
        q = *(const float4*)(base + 12); s12 = q.x*ing; s13 = q.y*ing; s14 = q.z*ing; s15 = q.w*ing;
    }

    // ---------------- 16 cascaded stages ----------------
    #pragma unroll 1
    for (int f = 0; f < NB; f++) {
        const float4 q0 = *(const float4*)&sc[f][frame][0];  // t00 t01 t10 t11
        const float4 q1 = *(const float4*)&sc[f][frame][4];  // b0 b1 c0 c1
        const float4 q2 = *(const float4*)&sc[f][frame][8];  // c2 M00 M01 M10
        const float  M11v = sc[f][frame][12];
        const float t00 = q0.x, t01 = q0.y, t10 = q0.z, t11 = q0.w;
        const float b0  = q1.x, b1  = q1.y, c0  = q1.z, c1  = q1.w;
        const float c2  = q2.x;

        // Phase A: zero-state run over own chunk -> affine constant
        float ic1 = 0.0f, ic2 = 0.0f;
        FOREACH_S(STEPA)

        // constants-only Kogge-Stone: wave-uniform M = T^16, M^d squared in place
        float Md00 = q2.y, Md01 = q2.z, Md10 = q2.w, Md11 = M11v;
        float Ac0 = ic1, Ac1 = ic2;
        #pragma unroll
        for (int d = 1; d < 64; d <<= 1) {
            const float lc0 = __shfl_up(Ac0, d);
            const float lc1 = __shfl_up(Ac1, d);
            if (lane >= d) {
                Ac0 = fmaf(Md00, lc0, fmaf(Md01, lc1, Ac0));
                Ac1 = fmaf(Md10, lc0, fmaf(Md11, lc1, Ac1));
            }
            const float n00 = Md00 * Md00 + Md01 * Md10;
            const float n01 = Md00 * Md01 + Md01 * Md11;
            const float n10 = Md10 * Md00 + Md11 * Md10;
            const float n11 = Md10 * Md01 + Md11 * Md11;
            Md00 = n00; Md01 = n01; Md10 = n10; Md11 = n11;
        }
        // Ac at lane 63 = wave aggregate constant

        const int buf = f & 1;
        if (lane == 63) sagg[buf][wave] = make_float2(Ac0, Ac1);

        // ce = exclusive constants -- issue pre-barrier, latency hides under it
        float ce0 = __shfl_up(Ac0, 1);
        float ce1 = __shfl_up(Ac1, 1);
        if (lane == 0) { ce0 = 0.0f; ce1 = 0.0f; }

        __syncthreads();   // the ONE barrier per round (sagg[buf] ready)

        const unsigned int tag = (unsigned int)(f + 1);
        unsigned int* stagebase = ws + ((size_t)(bt * NB + f) * NBLK) * 8;

        // -------- per-wave exclusive-prefix constant fold (wave-uniform) ----
        float Pc0 = 0.0f, Pc1 = 0.0f;
        #pragma unroll
        for (int j = 0; j < NWAVE - 1; j++) {
            if (j < wave) {
                const float2 a = sagg[buf][j];
                const float4 mw = sMw[f][j >> 1];
                const float n0 = fmaf(mw.x, Pc0, fmaf(mw.y, Pc1, a.x));
                const float n1 = fmaf(mw.z, Pc0, fmaf(mw.w, Pc1, a.y));
                Pc0 = n0; Pc1 = n1;
            }
        }

        // -------- wave 11: block-inclusive constant -> publish --------------
        if (wave == NWAVE - 1 && quarter < NBLK - 1) {
            const float2 a = sagg[buf][NWAVE - 1];
            const float4 mw = sMw[f][(NWAVE - 1) >> 1];
            const float i0 = fmaf(mw.x, Pc0, fmaf(mw.y, Pc1, a.x));
            const float i1 = fmaf(mw.z, Pc0, fmaf(mw.w, Pc1, a.y));
            if (lane == 0) {
                unsigned int* slot = stagebase + quarter * 8;
                float* dp = (float*)(slot + 1);
                __hip_atomic_store(&dp[0], i0, __ATOMIC_RELAXED, __HIP_MEMORY_SCOPE_AGENT);
                __hip_atomic_store(&dp[1], i1, __ATOMIC_RELAXED, __HIP_MEMORY_SCOPE_AGENT);
                __hip_atomic_store(slot, tag, __ATOMIC_RELEASE, __HIP_MEMORY_SCOPE_AGENT);
            }
        }

        // -------- block incoming state: lane-redundant polls + W fold -------
        float S0x = 0.0f, S0y = 0.0f;
        if (quarter > 0) {
            #pragma unroll
            for (int k = 0; k < NBLK - 1; k++) {
                if (k < quarter) {
                    unsigned int* slot = stagebase + k * 8;
                    while (__hip_atomic_load(slot, __ATOMIC_ACQUIRE, __HIP_MEMORY_SCOPE_AGENT) != tag) {
                        __builtin_amdgcn_s_sleep(1);
                    }
                    const float* dp = (const float*)(slot + 1);
                    const float cx = __hip_atomic_load(&dp[0], __ATOMIC_RELAXED, __HIP_MEMORY_SCOPE_AGENT);
                    const float cy = __hip_atomic_load(&dp[1], __ATOMIC_RELAXED, __HIP_MEMORY_SCOPE_AGENT);
                    const float4 w = sWm[f][k];
                    S0x += fmaf(w.x, cx, w.y * cy);
                    S0y += fmaf(w.z, cx, w.w * cy);
                }
            }
        }

        // -------- incoming wave state v = P_w * S0 + Pc_w (wave-uniform) ----
        const float4 pm = sPm[f][wave];
        const float vx = fmaf(pm.x, S0x, fmaf(pm.y, S0y, Pc0));
        const float vy = fmaf(pm.z, S0x, fmaf(pm.w, S0y, Pc1));

        // -------- distribute: ic = M^lane * v + ce (binexp, reg squaring) ---
        float w0 = vx, w1 = vy;
        float p00 = q2.y, p01 = q2.z, p10 = q2.w, p11 = M11v;
        #pragma unroll
        for (int b = 0; b < 6; b++) {
            if (lane & (1 << b)) {
                const float nw0 = fmaf(p00, w0, p01 * w1);
                const float nw1 = fmaf(p10, w0, p11 * w1);
                w0 = nw0; w1 = nw1;
            }
            if (b < 5) {
                const float n00 = p00 * p00 + p01 * p10;
                const float n01 = p00 * p01 + p01 * p11;
                const float n10 = p10 * p00 + p11 * p10;
                const float n11 = p10 * p01 + p11 * p11;
                p00 = n00; p01 = n01; p10 = n10; p11 = n11;
            }
        }
        float ic1r = w0 + ce0;
        float ic2r = w1 + ce1;
        ic1 = ic1r; ic2 = ic2r;

        // Phase C: true run from incoming state, write outputs in place
        FOREACH_S(STEPC)
    }

    // ---------------- store (with output gain) ----------------
    {
        const float og = sgain[1][frame];
        float* base = out + (size_t)bt * S + (size_t)(quarter * NCH + t) * CHUNK;
        float4 q;
        q.x = s00*og; q.y = s01*og; q.z = s02*og; q.w = s03*og; *(float4*)(base +  0) = q;
        q.x = s04*og; q.y = s05*og; q.z = s06*og; q.w = s07*og; *(float4*)(base +  4) = q;
        q.x = s08*og; q.y = s09*og; q.z = s10*og; q.w = s11*og; *(float4*)(base +  8) = q;
        q.x = s12*og; q.y = s13*og; q.z = s14*og; q.w = s15*og; *(float4*)(base + 12) = q;
    }
}

extern "C" void kernel_launch(void* const* d_in, const int* in_sizes, int n_in,
                              void* d_out, int out_size, void* d_ws, size_t ws_size,
                              hipStream_t stream)
{
    const float* audio  = (const float*)d_in[0];
    const float* params = (const float*)d_in[1];
    float* out = (float*)d_out;
    unsigned int* ws = (unsigned int*)d_ws;
    biquad_chain_kernel<<<NBLK * NBATCH, NCH, 0, stream>>>(audio, params, out, ws);
}

// Round 13
// 222.231 us; speedup vs baseline: 1.5831x; 1.5831x over previous
//
#include <hip/hip_runtime.h>
#include <math.h>

#define NBATCH 32
#define S      49152
#define NF     24          // frames (2048 samples each)
#define NB     16          // biquads
#define NBLK   16          // blocks per batch (R21: 2 blocks/CU)
#define CHUNK  8           // samples per lane (wave = 512 samples)
#define NCH    384         // threads per block (6 waves)
#define NWAVE  6           // waves per block
// R21 = R16 machinery (best clean, 71.5us) in HALF-SIZE blocks: 512 blocks x
// 6 waves = 2 independent barrier domains per CU at the same 12 waves/CU TLP.
// Evidence R9-R20: every intra-block restructure is null/negative; counters
// (VALU 19%, HBM 2%) + critical-path arithmetic leave a ~5x wall residue.
// Remaining untested hypothesis: stalls are BLOCK-correlated (one block/CU,
// all 12 waves hit barrier/KS/spin together -> CU idles as a unit). R12 did
// NOT test this (768-thr blocks, still 1/CU monolithic barrier). With 2
// blocks/CU, block A's barrier/spin phases overlap block B's issue phases.
// Wave covers 512 samples (wave-frame purity: 512 | 2048); combine uses
// per-frame T^512 powers; poll fan <=15, parallel + butterfly sum.
// Health: WRITE ~7MB (scratch check), VGPR <= ~64, absmax 0.015625.

__device__ __forceinline__ float clampf(float x, float lo, float hi) {
    return fminf(fmaxf(x, lo), hi);
}

// 8 named scalar signal registers (SSA-guaranteed; arrays spill).
#define FOREACH_S(OP) \
    OP(s00) OP(s01) OP(s02) OP(s03) OP(s04) OP(s05) OP(s06) OP(s07)

#define DECL_S(x) float x;

// Phase A step: state only.  s' = T s + b*x
#define STEPA(x) { \
    const float n1_ = fmaf(t00, ic1, fmaf(t01, ic2, b0 * (x))); \
    const float n2_ = fmaf(t10, ic1, fmaf(t11, ic2, b1 * (x))); \
    ic1 = n1_; ic2 = n2_; }

// Phase C step: output + state.  y = c0*ic1 + c1*ic2 + c2*x, in place.
#define STEPC(x) { \
    const float y_  = fmaf(c0, ic1, fmaf(c1, ic2, c2 * (x))); \
    const float n1_ = fmaf(t00, ic1, fmaf(t01, ic2, b0 * (x))); \
    const float n2_ = fmaf(t10, ic1, fmaf(t11, ic2, b1 * (x))); \
    (x) = y_; ic1 = n1_; ic2 = n2_; }

__global__ __launch_bounds__(NCH, 3)
void biquad_chain_kernel(const float* __restrict__ audio,
                         const float* __restrict__ params,
                         float* __restrict__ out,
                         unsigned int* __restrict__ ws)
{
    __shared__ __align__(16) float sc[NB][NF][16];  // affine(9) + T^8(4)
    __shared__ float4 sT512[NB][NF];      // per-frame T^512 (init/prefix)
    __shared__ float4 sMw[NB][NWAVE];     // wave aggregate T^512 (local waves)
    __shared__ float4 sPm[NB][NWAVE];     // exclusive wave-prefix P_w
    __shared__ float4 sWm[NB][NBLK - 1];  // pred-block fold matrices W_k
    __shared__ float  sgain[2][NF];       // [0]=in gain, [1]=out gain
    __shared__ float2 sagg[2][NWAVE];     // runtime wave constants (dbuf)
    __shared__ float2 sv[NWAVE];          // per-wave incoming state
    __shared__ unsigned int sflag[NB];    // per-stage sv-ready flag

    const int t       = threadIdx.x;
    // XCD co-location swizzle: all 16 blocks of a batch on one XCD.
    const int xcd     = blockIdx.x & 7;
    const int slot_   = blockIdx.x >> 3;          // 0..63
    const int bt      = xcd * 4 + (slot_ & 3);    // batch
    const int blk     = slot_ >> 2;               // 16th of the signal (0..15)
    const int lane    = t & 63;
    const int wave    = t >> 6;                   // 0..5
    const int frame   = (blk * NWAVE + wave) >> 2; // global frame of this wave

    // ---------------- coefficient init (all 384 threads) ----------------
    if (t < NB * NF) {
        const int f  = t / NF;
        const int fr = t % NF;
        const float* P = params + (size_t)bt * 50 * NF;
        const float fn = P[(3 * f + 0) * NF + fr];
        const float gn = P[(3 * f + 1) * NF + fr];
        const float qn = P[(3 * f + 2) * NF + fr];

        float Q = __expf(-0.69314718f + qn * 3.4657359f);
        Q = clampf(Q, 0.1f, 100.0f);

        float lo, hi;
        int type;                        // 0 hp, 1 lp, 2 peak, 3 lowshelf, 4 highshelf
        if      (f == 0)  { lo = 20.0f;   hi = 500.0f;   type = 0; }
        else if (f == 15) { lo = 5000.0f; hi = 20000.0f; type = 1; }
        else if (f == 1)  { lo = 50.0f;   hi = 16000.0f; type = 3; }
        else if (f == 14) { lo = 50.0f;   hi = 16000.0f; type = 4; }
        else              { lo = 100.0f;  hi = 15000.0f; type = 2; }

        const float fc = __expf(__logf(lo) + fn * (__logf(hi) - __logf(lo)));
        float g_ = __tanf((float)M_PI * fc / 96000.0f);   // angle <= 0.655 rad
        g_ = clampf(g_, 1e-6f, 100.0f);
        const float gdb = -24.0f + 48.0f * gn;

        float a1, a2, a3, m0, m1, m2;
        if (type == 0 || type == 1) {
            const float k = 1.0f / Q;
            a1 = 1.0f / (1.0f + g_ * (g_ + k)); a2 = g_ * a1; a3 = g_ * a2;
            if (type == 0) { m0 = 1.0f; m1 = -k;   m2 = -1.0f; }
            else           { m0 = 0.0f; m1 = 0.0f; m2 = 1.0f;  }
        } else if (type == 2) {
            const float A = __expf(gdb * (2.30258509f / 40.0f));
            const float k = (gdb >= 0.0f) ? 1.0f / (Q * A) : A / Q;
            a1 = 1.0f / (1.0f + g_ * (g_ + k)); a2 = g_ * a1; a3 = g_ * a2;
            m0 = 1.0f; m1 = k * (A * A - 1.0f); m2 = 0.0f;
        } else {
            const float A  = __expf(gdb * (2.30258509f / 40.0f));
            const float sA = sqrtf(A);
            const float k  = 1.0f / Q;
            float gs;
            if (type == 3) gs = (gdb >= 0.0f) ? g_ / sA : g_ * sA;
            else           gs = (gdb >= 0.0f) ? g_ * sA : g_ / sA;
            a1 = 1.0f / (1.0f + gs * (gs + k)); a2 = gs * a1; a3 = gs * a2;
            if (type == 3) { m0 = 1.0f;  m1 = k * (A - 1.0f);      m2 = A * A - 1.0f; }
            else           { m0 = A * A; m1 = k * (1.0f - A) * A;  m2 = 1.0f - A * A; }
        }

        // affine per-sample form: s' = T s + b*x ; y = c0*s1 + c1*s2 + c2*x
        const float q2  = a2 * a2 + a3;
        const float t00 = 2.0f * a1 - 1.0f;
        const float t01 = -2.0f * a2;
        const float t10 = 2.0f * a1 * a2;
        const float t11 = 1.0f - 2.0f * q2;
        const float b0  = 2.0f * a2;
        const float b1  = 2.0f * q2;
        const float c0  = a1 * (m1 + m2 * a2);
        const float c1  = m2 * (1.0f - q2) - m1 * a2;
        const float c2  = m0 + m1 * a2 + m2 * q2;

        // T^8 by 3 squarings (CHUNK=8) -- KS/binexp base
        float u00 = t00, u01 = t01, u10 = t10, u11 = t11;
        #pragma unroll
        for (int i = 0; i < 3; i++) {
            const float n00 = u00 * u00 + u01 * u10;
            const float n01 = u00 * u01 + u01 * u11;
            const float n10 = u10 * u00 + u11 * u10;
            const float n11 = u10 * u01 + u11 * u11;
            u00 = n00; u01 = n01; u10 = n10; u11 = n11;
        }
        sc[f][fr][0] = t00; sc[f][fr][1] = t01; sc[f][fr][2] = t10; sc[f][fr][3] = t11;
        sc[f][fr][4] = b0;  sc[f][fr][5] = b1;  sc[f][fr][6] = c0;  sc[f][fr][7] = c1;
        sc[f][fr][8] = c2;  sc[f][fr][9] = u00; sc[f][fr][10] = u01; sc[f][fr][11] = u10;
        sc[f][fr][12] = u11;

        // continue squaring: T^8 -> T^512 (6 more squarings) -- wave aggregate
        #pragma unroll
        for (int i = 0; i < 6; i++) {
            const float n00 = u00 * u00 + u01 * u10;
            const float n01 = u00 * u01 + u01 * u11;
            const float n10 = u10 * u00 + u11 * u10;
            const float n11 = u10 * u01 + u11 * u11;
            u00 = n00; u01 = n01; u10 = n10; u11 = n11;
        }
        sT512[f][fr] = make_float4(u00, u01, u10, u11);
    }
    if (t < 2 * NF) {
        const int which = t / NF;       // 0 = in gain (row 48), 1 = out gain (49)
        const int fr    = t % NF;
        const float* P = params + (size_t)bt * 50 * NF;
        const float p  = P[(48 + which) * NF + fr];
        const float db = -60.0f + 60.0f * p;
        sgain[which][fr] = __expf(db * (2.30258509f / 20.0f));
    }
    if (t < NB) sflag[t] = 0u;
    __syncthreads();

    // ------- prefix assembly (threads 0..15, one per stage) -------
    if (t < NB) {
        const int f = t;
        // wave aggregates (T^512 of each local wave's frame)
        #pragma unroll
        for (int w = 0; w < NWAVE; w++) {
            sMw[f][w] = sT512[f][(blk * NWAVE + w) >> 2];
        }
        // exclusive wave prefixes P_w = M_{w-1} * ... * M_0
        float q00 = 1.0f, q01 = 0.0f, q10 = 0.0f, q11 = 1.0f;
        #pragma unroll
        for (int w = 0; w < NWAVE; w++) {
            sPm[f][w] = make_float4(q00, q01, q10, q11);
            const float4 mw = sMw[f][w];
            const float n00 = mw.x * q00 + mw.y * q10;
            const float n01 = mw.x * q01 + mw.y * q11;
            const float n10 = mw.z * q00 + mw.w * q10;
            const float n11 = mw.z * q01 + mw.w * q11;
            q00 = n00; q01 = n01; q10 = n10; q11 = n11;
        }
        // pred-block fold matrices: W_{blk-1}=I ; W_{k-1} = W_k * B_k
        if (blk > 0) {
            float r00 = 1.0f, r01 = 0.0f, r10 = 0.0f, r11 = 1.0f;
            for (int k = blk - 1; k >= 0; k--) {
                sWm[f][k] = make_float4(r00, r01, r10, r11);
                if (k > 0) {
                    // B_k = product of T^512 over half-quarters 6k..6k+5
                    float b00 = 1.0f, b01 = 0.0f, b10 = 0.0f, b11 = 1.0f;
                    #pragma unroll
                    for (int m = 0; m < NWAVE; m++) {
                        const float4 g = sT512[f][(6 * k + m) >> 2];
                        const float n00 = g.x * b00 + g.y * b10;
                        const float n01 = g.x * b01 + g.y * b11;
                        const float n10 = g.z * b00 + g.w * b10;
                        const float n11 = g.z * b01 + g.w * b11;
                        b00 = n00; b01 = n01; b10 = n10; b11 = n11;
                    }
                    const float n00 = r00 * b00 + r01 * b10;
                    const float n01 = r00 * b01 + r01 * b11;
                    const float n10 = r10 * b00 + r11 * b10;
                    const float n11 = r10 * b01 + r11 * b11;
                    r00 = n00; r01 = n01; r10 = n10; r11 = n11;
                }
            }
        }
    }
    __syncthreads();

    // ---------------- load chunk (with input gain) ----------------
    FOREACH_S(DECL_S)
    {
        const float ing = sgain[0][frame];
        const float* base = audio + (size_t)bt * S + (size_t)blk * (NCH * CHUNK)
                          + (size_t)t * CHUNK;
        float4 q;
        q = *(const float4*)(base + 0); s00 = q.x*ing; s01 = q.y*ing; s02 = q.z*ing; s03 = q.w*ing;
        q = *(const float4*)(base + 4); s04 = q.x*ing; s05 = q.y*ing; s06 = q.z*ing; s07 = q.w*ing;
    }

    // ---------------- 16 cascaded stages ----------------
    #pragma unroll 1
    for (int f = 0; f < NB; f++) {
        const float4 q0 = *(const float4*)&sc[f][frame][0];  // t00 t01 t10 t11
        const float4 q1 = *(const float4*)&sc[f][frame][4];  // b0 b1 c0 c1
        const float4 q2 = *(const float4*)&sc[f][frame][8];  // c2 M00 M01 M10
        const float  M11v = sc[f][frame][12];
        const float t00 = q0.x, t01 = q0.y, t10 = q0.z, t11 = q0.w;
        const float b0  = q1.x, b1  = q1.y, c0  = q1.z, c1  = q1.w;
        const float c2  = q2.x;

        // Phase A: zero-state run over own chunk -> affine constant
        float ic1 = 0.0f, ic2 = 0.0f;
        FOREACH_S(STEPA)

        // constants-only Kogge-Stone: wave-uniform M = T^8, M^d squared in place
        float Md00 = q2.y, Md01 = q2.z, Md10 = q2.w, Md11 = M11v;
        float Ac0 = ic1, Ac1 = ic2;
        #pragma unroll
        for (int d = 1; d < 64; d <<= 1) {
            const float lc0 = __shfl_up(Ac0, d);
            const float lc1 = __shfl_up(Ac1, d);
            if (lane >= d) {
                Ac0 = fmaf(Md00, lc0, fmaf(Md01, lc1, Ac0));
                Ac1 = fmaf(Md10, lc0, fmaf(Md11, lc1, Ac1));
            }
            const float n00 = Md00 * Md00 + Md01 * Md10;
            const float n01 = Md00 * Md01 + Md01 * Md11;
            const float n10 = Md10 * Md00 + Md11 * Md10;
            const float n11 = Md10 * Md01 + Md11 * Md11;
            Md00 = n00; Md01 = n01; Md10 = n10; Md11 = n11;
        }
        // Ac at lane 63 = wave aggregate constant

        const int buf = f & 1;
        if (lane == 63) sagg[buf][wave] = make_float2(Ac0, Ac1);

        // ce = exclusive constants -- issue pre-barrier, latency hides under it
        float ce0 = __shfl_up(Ac0, 1);
        float ce1 = __shfl_up(Ac1, 1);
        if (lane == 0) { ce0 = 0.0f; ce1 = 0.0f; }

        __syncthreads();   // the ONE barrier per round (sagg[buf] ready)

        const unsigned int tag = (unsigned int)(f + 1);
        unsigned int* stagebase = ws + ((size_t)(bt * NB + f) * NBLK) * 4;

        if (wave == 0) {
            // predicated 6-step constants fold (precomputed M_w from LDS)
            float Pc0 = 0.0f, Pc1 = 0.0f;
            #pragma unroll
            for (int j = 0; j < NWAVE; j++) {
                const float2 a = sagg[buf][j];
                const float4 mw = sMw[f][j];
                if (lane > j) {
                    const float n0 = fmaf(mw.x, Pc0, fmaf(mw.y, Pc1, a.x));
                    const float n1 = fmaf(mw.z, Pc0, fmaf(mw.w, Pc1, a.y));
                    Pc0 = n0; Pc1 = n1;
                }
            }

            // publish block-own inclusive constant (lane 6) ASAP
            if (blk < NBLK - 1 && lane == NWAVE) {
                unsigned int* slot = stagebase + blk * 4;
                float* dp = (float*)(slot + 1);
                __hip_atomic_store(&dp[0], Pc0, __ATOMIC_RELAXED, __HIP_MEMORY_SCOPE_AGENT);
                __hip_atomic_store(&dp[1], Pc1, __ATOMIC_RELAXED, __HIP_MEMORY_SCOPE_AGENT);
                __hip_atomic_store(slot, tag, __ATOMIC_RELEASE, __HIP_MEMORY_SCOPE_AGENT);
            }

            // block incoming state: PARALLEL polls + precomputed-W fold
            float S0x = 0.0f, S0y = 0.0f;
            if (blk > 0) {
                float ux = 0.0f, uy = 0.0f;
                if (lane < blk) {
                    unsigned int* slot = stagebase + lane * 4;
                    while (__hip_atomic_load(slot, __ATOMIC_ACQUIRE, __HIP_MEMORY_SCOPE_AGENT) != tag) {
                        __builtin_amdgcn_s_sleep(1);
                    }
                    const float* dp = (const float*)(slot + 1);
                    const float cx = __hip_atomic_load(&dp[0], __ATOMIC_RELAXED, __HIP_MEMORY_SCOPE_AGENT);
                    const float cy = __hip_atomic_load(&dp[1], __ATOMIC_RELAXED, __HIP_MEMORY_SCOPE_AGENT);
                    const float4 w = sWm[f][lane];
                    ux = fmaf(w.x, cx, w.y * cy);
                    uy = fmaf(w.z, cx, w.w * cy);
                }
                // butterfly sum over lanes 0..15 (lanes >= blk contribute 0)
                #pragma unroll
                for (int d = 1; d < 16; d <<= 1) {
                    ux += __shfl_xor(ux, d);
                    uy += __shfl_xor(uy, d);
                }
                S0x = __shfl(ux, 0);
                S0y = __shfl(uy, 0);
            }

            // per-wave incoming state v = P_w * S0 + Pc_w ; lanes 0..5
            if (lane < NWAVE) {
                const float4 pm = sPm[f][lane];
                sv[lane] = make_float2(
                    fmaf(pm.x, S0x, fmaf(pm.y, S0y, Pc0)),
                    fmaf(pm.z, S0x, fmaf(pm.w, S0y, Pc1)));
            }
            if (lane == 0) {
                __hip_atomic_store(&sflag[f], tag, __ATOMIC_RELEASE,
                                   __HIP_MEMORY_SCOPE_WORKGROUP);
            }
        } else {
            // ready-flag spin: proceed the moment sv is written
            while (__hip_atomic_load(&sflag[f], __ATOMIC_ACQUIRE,
                                     __HIP_MEMORY_SCOPE_WORKGROUP) != tag)
                __builtin_amdgcn_s_sleep(1);
        }

        const float2 v = sv[wave];

        // distribute: ic = M^lane * v + ce (binexp with register squaring)
        float w0 = v.x, w1 = v.y;
        float p00 = q2.y, p01 = q2.z, p10 = q2.w, p11 = M11v;
        #pragma unroll
        for (int b = 0; b < 6; b++) {
            if (lane & (1 << b)) {
                const float nw0 = fmaf(p00, w0, p01 * w1);
                const float nw1 = fmaf(p10, w0, p11 * w1);
                w0 = nw0; w1 = nw1;
            }
            if (b < 5) {
                const float n00 = p00 * p00 + p01 * p10;
                const float n01 = p00 * p01 + p01 * p11;
                const float n10 = p10 * p00 + p11 * p10;
                const float n11 = p10 * p01 + p11 * p11;
                p00 = n00; p01 = n01; p10 = n10; p11 = n11;
            }
        }
        ic1 = w0 + ce0;
        ic2 = w1 + ce1;

        // Phase C: true run from incoming state, write outputs in place
        FOREACH_S(STEPC)
    }

    // ---------------- store (with output gain) ----------------
    {
        const float og = sgain[1][frame];
        float* base = out + (size_t)bt * S + (size_t)blk * (NCH * CHUNK)
                    + (size_t)t * CHUNK;
        float4 q;
        q.x = s00*og; q.y = s01*og; q.z = s02*og; q.w = s03*og; *(float4*)(base + 0) = q;
        q.x = s04*og; q.y = s05*og; q.z = s06*og; q.w = s07*og; *(float4*)(base + 4) = q;
    }
}

extern "C" void kernel_launch(void* const* d_in, const int* in_sizes, int n_in,
                              void* d_out, int out_size, void* d_ws, size_t ws_size,
                              hipStream_t stream)
{
    const float* audio  = (const float*)d_in[0];
    const float* params = (const float*)d_in[1];
    float* out = (float*)d_out;
    unsigned int* ws = (unsigned int*)d_ws;
    biquad_chain_kernel<<<NBLK * NBATCH, NCH, 0, stream>>>(audio, params, out, ws);
}

// Round 14
// 111.745 us; speedup vs baseline: 3.1484x; 1.9887x over previous
//
#include <hip/hip_runtime.h>
#include <math.h>

#define NBATCH 32
#define S      49152
#define NF     24          // frames (2048 samples each)
#define NB     16          // biquads
#define NBLK   4           // blocks per batch (R9-proven best)
#define CHUNK  16          // samples per thread (R9-proven; 32 spills)
#define NCH    768         // threads per block
#define NWAVE  12          // waves per block
// R22 = R16 (best clean, 71.5us) with the post-barrier serial segment cut.
// Ledger: R10-R21 all null/regress; R16 optimal. Its post-barrier chain is
// wave0{fold12 -> publish -> poll -> sv compute -> sv write -> sflag} with 11
// waves spinning, then sv read. R22 recombines two VERIFIED pieces: R20
// proved the distributed per-wave Pc fold correct (its regression was the
// distributed L2 POLL, not the fold); R16 proved the single-poller protocol.
//  - every wave folds its own exclusive Pc_w from sagg (parallel, LDS bcast)
//  - wave 11 publishes block-inclusive from its lane-63 registers (no S0 dep)
//  - wave 0 ONLY polls (quarter>0) and publishes 2-float S0 + flag
//  - all waves compute v = P_w*S0 + Pc_w locally; quarter-0 blocks: NO spin
// Serial segment: (poll + 2-float write + detect) only. ~300-400 cy/round
// shorter for quarter>0; quarter-0 blocks lose the spin entirely.
// Health: WRITE ~7MB, VGPR <= ~68, absmax 0.015625.

__device__ __forceinline__ float clampf(float x, float lo, float hi) {
    return fminf(fmaxf(x, lo), hi);
}

// 16 named scalar signal registers (SSA-guaranteed; arrays spill).
#define FOREACH_S(OP) \
    OP(s00) OP(s01) OP(s02) OP(s03) OP(s04) OP(s05) OP(s06) OP(s07) \
    OP(s08) OP(s09) OP(s10) OP(s11) OP(s12) OP(s13) OP(s14) OP(s15)

#define DECL_S(x) float x;

// Phase A step: state only.  s' = T s + b*x
#define STEPA(x) { \
    const float n1_ = fmaf(t00, ic1, fmaf(t01, ic2, b0 * (x))); \
    const float n2_ = fmaf(t10, ic1, fmaf(t11, ic2, b1 * (x))); \
    ic1 = n1_; ic2 = n2_; }

// Phase C step: output + state.  y = c0*ic1 + c1*ic2 + c2*x, in place.
#define STEPC(x) { \
    const float y_  = fmaf(c0, ic1, fmaf(c1, ic2, c2 * (x))); \
    const float n1_ = fmaf(t00, ic1, fmaf(t01, ic2, b0 * (x))); \
    const float n2_ = fmaf(t10, ic1, fmaf(t11, ic2, b1 * (x))); \
    (x) = y_; ic1 = n1_; ic2 = n2_; }

__global__ __launch_bounds__(NCH, 3)
void biquad_chain_kernel(const float* __restrict__ audio,
                         const float* __restrict__ params,
                         float* __restrict__ out,
                         unsigned int* __restrict__ ws)
{
    __shared__ __align__(16) float sc[NB][NF][16];  // affine(9) + T^16(4)
    __shared__ float4 sMw[NB][6];         // T^1024 per local frame
    __shared__ float4 sPm[NB][NWAVE];     // exclusive wave-prefix P_w
    __shared__ float4 sWm[NB][3];         // pred-quarter fold matrices W_k
    __shared__ float4 sT2048[NB][NF];     // frame aggregates (init/prefix only)
    __shared__ float  sgain[2][NF];       // [0]=in gain, [1]=out gain
    __shared__ float2 sagg[2][NWAVE];     // runtime wave constants (dbuf)
    __shared__ float2 sS0;                // block incoming state (wave-0 publish)
    __shared__ unsigned int sflag[NB];    // per-stage S0-ready flag

    const int t       = threadIdx.x;
    // XCD co-location swizzle: all 4 quarters of a batch on one XCD.
    const int xcd     = blockIdx.x & 7;
    const int slot_   = blockIdx.x >> 3;
    const int bt      = xcd * 4 + (slot_ & 3);   // batch
    const int quarter = slot_ >> 2;              // which quarter of the signal
    const int lane    = t & 63;
    const int wave    = t >> 6;
    const int frame   = quarter * 6 + (wave >> 1);  // 2 waves per 2048-frame

    // ---------------- coefficient init (threads 0..383) ----------------
    if (t < NB * NF) {
        const int f  = t / NF;
        const int fr = t % NF;
        const float* P = params + (size_t)bt * 50 * NF;
        const float fn = P[(3 * f + 0) * NF + fr];
        const float gn = P[(3 * f + 1) * NF + fr];
        const float qn = P[(3 * f + 2) * NF + fr];

        float Q = __expf(-0.69314718f + qn * 3.4657359f);
        Q = clampf(Q, 0.1f, 100.0f);

        float lo, hi;
        int type;                        // 0 hp, 1 lp, 2 peak, 3 lowshelf, 4 highshelf
        if      (f == 0)  { lo = 20.0f;   hi = 500.0f;   type = 0; }
        else if (f == 15) { lo = 5000.0f; hi = 20000.0f; type = 1; }
        else if (f == 1)  { lo = 50.0f;   hi = 16000.0f; type = 3; }
        else if (f == 14) { lo = 50.0f;   hi = 16000.0f; type = 4; }
        else              { lo = 100.0f;  hi = 15000.0f; type = 2; }

        const float fc = __expf(__logf(lo) + fn * (__logf(hi) - __logf(lo)));
        float g_ = __tanf((float)M_PI * fc / 96000.0f);   // angle <= 0.655 rad
        g_ = clampf(g_, 1e-6f, 100.0f);
        const float gdb = -24.0f + 48.0f * gn;

        float a1, a2, a3, m0, m1, m2;
        if (type == 0 || type == 1) {
            const float k = 1.0f / Q;
            a1 = 1.0f / (1.0f + g_ * (g_ + k)); a2 = g_ * a1; a3 = g_ * a2;
            if (type == 0) { m0 = 1.0f; m1 = -k;   m2 = -1.0f; }
            else           { m0 = 0.0f; m1 = 0.0f; m2 = 1.0f;  }
        } else if (type == 2) {
            const float A = __expf(gdb * (2.30258509f / 40.0f));
            const float k = (gdb >= 0.0f) ? 1.0f / (Q * A) : A / Q;
            a1 = 1.0f / (1.0f + g_ * (g_ + k)); a2 = g_ * a1; a3 = g_ * a2;
            m0 = 1.0f; m1 = k * (A * A - 1.0f); m2 = 0.0f;
        } else {
            const float A  = __expf(gdb * (2.30258509f / 40.0f));
            const float sA = sqrtf(A);
            const float k  = 1.0f / Q;
            float gs;
            if (type == 3) gs = (gdb >= 0.0f) ? g_ / sA : g_ * sA;
            else           gs = (gdb >= 0.0f) ? g_ * sA : g_ / sA;
            a1 = 1.0f / (1.0f + gs * (gs + k)); a2 = gs * a1; a3 = gs * a2;
            if (type == 3) { m0 = 1.0f;  m1 = k * (A - 1.0f);      m2 = A * A - 1.0f; }
            else           { m0 = A * A; m1 = k * (1.0f - A) * A;  m2 = 1.0f - A * A; }
        }

        // affine per-sample form: s' = T s + b*x ; y = c0*s1 + c1*s2 + c2*x
        const float q2  = a2 * a2 + a3;
        const float t00 = 2.0f * a1 - 1.0f;
        const float t01 = -2.0f * a2;
        const float t10 = 2.0f * a1 * a2;
        const float t11 = 1.0f - 2.0f * q2;
        const float b0  = 2.0f * a2;
        const float b1  = 2.0f * q2;
        const float c0  = a1 * (m1 + m2 * a2);
        const float c1  = m2 * (1.0f - q2) - m1 * a2;
        const float c2  = m0 + m1 * a2 + m2 * q2;

        // T^16 by 4 squarings
        float u00 = t00, u01 = t01, u10 = t10, u11 = t11;
        #pragma unroll
        for (int i = 0; i < 4; i++) {
            const float n00 = u00 * u00 + u01 * u10;
            const float n01 = u00 * u01 + u01 * u11;
            const float n10 = u10 * u00 + u11 * u10;
            const float n11 = u10 * u01 + u11 * u11;
            u00 = n00; u01 = n01; u10 = n10; u11 = n11;
        }
        sc[f][fr][0] = t00; sc[f][fr][1] = t01; sc[f][fr][2] = t10; sc[f][fr][3] = t11;
        sc[f][fr][4] = b0;  sc[f][fr][5] = b1;  sc[f][fr][6] = c0;  sc[f][fr][7] = c1;
        sc[f][fr][8] = c2;  sc[f][fr][9] = u00; sc[f][fr][10] = u01; sc[f][fr][11] = u10;
        sc[f][fr][12] = u11;

        // continue squaring: T^16 -> T^1024 (6 more squarings)
        #pragma unroll
        for (int i = 0; i < 6; i++) {
            const float n00 = u00 * u00 + u01 * u10;
            const float n01 = u00 * u01 + u01 * u11;
            const float n10 = u10 * u00 + u11 * u10;
            const float n11 = u10 * u01 + u11 * u11;
            u00 = n00; u01 = n01; u10 = n10; u11 = n11;
        }
        const int lfr = fr - quarter * 6;
        if (lfr >= 0 && lfr < 6) {
            sMw[f][lfr] = make_float4(u00, u01, u10, u11);
        }
        // one more squaring: T^2048 (frame aggregate, ALL frames)
        {
            const float n00 = u00 * u00 + u01 * u10;
            const float n01 = u00 * u01 + u01 * u11;
            const float n10 = u10 * u00 + u11 * u10;
            const float n11 = u10 * u01 + u11 * u11;
            sT2048[f][fr] = make_float4(n00, n01, n10, n11);
        }
    }
    if (t >= 384 && t < 384 + 2 * NF) {
        const int idx = t - 384;
        const int which = idx / NF;     // 0 = in gain (row 48), 1 = out gain (row 49)
        const int fr    = idx % NF;
        const float* P = params + (size_t)bt * 50 * NF;
        const float p  = P[(48 + which) * NF + fr];
        const float db = -60.0f + 60.0f * p;
        sgain[which][fr] = __expf(db * (2.30258509f / 20.0f));
    }
    if (t < NB) sflag[t] = 0u;
    __syncthreads();

    // ------- prefix assembly (threads 0..15, one per stage) -------
    if (t < NB) {
        const int f = t;
        // exclusive wave prefixes P_w over local frames (Q = running product)
        float q00 = 1.0f, q01 = 0.0f, q10 = 0.0f, q11 = 1.0f;
        #pragma unroll
        for (int k = 0; k < 6; k++) {
            sPm[f][2 * k] = make_float4(q00, q01, q10, q11);
            const float4 mw = sMw[f][k];
            sPm[f][2 * k + 1] = make_float4(
                mw.x * q00 + mw.y * q10, mw.x * q01 + mw.y * q11,
                mw.z * q00 + mw.w * q10, mw.z * q01 + mw.w * q11);
            const float4 g = sT2048[f][quarter * 6 + k];
            const float n00 = g.x * q00 + g.y * q10;
            const float n01 = g.x * q01 + g.y * q11;
            const float n10 = g.z * q00 + g.w * q10;
            const float n11 = g.z * q01 + g.w * q11;
            q00 = n00; q01 = n01; q10 = n10; q11 = n11;
        }
        // pred-quarter fold matrices: W_{q-1}=I ; W_k = W_{k+1} * B_{k+1}
        if (quarter > 0) {
            float r00 = 1.0f, r01 = 0.0f, r10 = 0.0f, r11 = 1.0f;
            for (int k = quarter - 1; k >= 0; k--) {
                sWm[f][k] = make_float4(r00, r01, r10, r11);
                if (k > 0) {
                    float b00 = 1.0f, b01 = 0.0f, b10 = 0.0f, b11 = 1.0f;
                    #pragma unroll
                    for (int m = 0; m < 6; m++) {
                        const float4 g = sT2048[f][6 * k + m];
                        const float n00 = g.x * b00 + g.y * b10;
                        const float n01 = g.x * b01 + g.y * b11;
                        const float n10 = g.z * b00 + g.w * b10;
                        const float n11 = g.z * b01 + g.w * b11;
                        b00 = n00; b01 = n01; b10 = n10; b11 = n11;
                    }
                    const float n00 = r00 * b00 + r01 * b10;
                    const float n01 = r00 * b01 + r01 * b11;
                    const float n10 = r10 * b00 + r11 * b10;
                    const float n11 = r10 * b01 + r11 * b11;
                    r00 = n00; r01 = n01; r10 = n10; r11 = n11;
                }
            }
        }
    }
    __syncthreads();

    // ---------------- load chunk (with input gain) ----------------
    FOREACH_S(DECL_S)
    {
        const float ing = sgain[0][frame];
        const float* base = audio + (size_t)bt * S
                          + (size_t)(quarter * NCH + t) * CHUNK;
        float4 q;
        q = *(const float4*)(base +  0); s00 = q.x*ing; s01 = q.y*ing; s02 = q.z*ing; s03 = q.w*ing;
        q = *(const float4*)(base +  4); s04 = q.x*ing; s05 = q.y*ing; s06 = q.z*ing; s07 = q.w*ing;
        q = *(const float4*)(base +  8); s08 = q.x*ing; s09 = q.y*ing; s10 = q.z*ing; s11 = q.w*ing;
        q = *(const float4*)(base + 12); s12 = q.x*ing; s13 = q.y*ing; s14 = q.z*ing; s15 = q.w*ing;
    }

    // ---------------- 16 cascaded stages ----------------
    #pragma unroll 1
    for (int f = 0; f < NB; f++) {
        const float4 q0 = *(const float4*)&sc[f][frame][0];  // t00 t01 t10 t11
        const float4 q1 = *(const float4*)&sc[f][frame][4];  // b0 b1 c0 c1
        const float4 q2 = *(const float4*)&sc[f][frame][8];  // c2 M00 M01 M10
        const float  M11v = sc[f][frame][12];
        const float t00 = q0.x, t01 = q0.y, t10 = q0.z, t11 = q0.w;
        const float b0  = q1.x, b1  = q1.y, c0  = q1.z, c1  = q1.w;
        const float c2  = q2.x;

        // Phase A: zero-state run over own chunk -> affine constant
        float ic1 = 0.0f, ic2 = 0.0f;
        FOREACH_S(STEPA)

        // constants-only Kogge-Stone: wave-uniform M = T^16, M^d squared in place
        float Md00 = q2.y, Md01 = q2.z, Md10 = q2.w, Md11 = M11v;
        float Ac0 = ic1, Ac1 = ic2;
        #pragma unroll
        for (int d = 1; d < 64; d <<= 1) {
            const float lc0 = __shfl_up(Ac0, d);
            const float lc1 = __shfl_up(Ac1, d);
            if (lane >= d) {
                Ac0 = fmaf(Md00, lc0, fmaf(Md01, lc1, Ac0));
                Ac1 = fmaf(Md10, lc0, fmaf(Md11, lc1, Ac1));
            }
            const float n00 = Md00 * Md00 + Md01 * Md10;
            const float n01 = Md00 * Md01 + Md01 * Md11;
            const float n10 = Md10 * Md00 + Md11 * Md10;
            const float n11 = Md10 * Md01 + Md11 * Md11;
            Md00 = n00; Md01 = n01; Md10 = n10; Md11 = n11;
        }
        // Ac at lane 63 = wave aggregate constant

        const int buf = f & 1;
        if (lane == 63) sagg[buf][wave] = make_float2(Ac0, Ac1);

        // ce = exclusive constants -- issue pre-barrier, latency hides under it
        float ce0 = __shfl_up(Ac0, 1);
        float ce1 = __shfl_up(Ac1, 1);
        if (lane == 0) { ce0 = 0.0f; ce1 = 0.0f; }

        __syncthreads();   // the ONE barrier per round (sagg[buf] ready)

        const unsigned int tag = (unsigned int)(f + 1);
        unsigned int* stagebase = ws + ((size_t)(bt * NB + f) * NBLK) * 8;

        // -------- per-wave exclusive-prefix constant fold (parallel) --------
        // (R20-verified algebra; LDS broadcast reads, wave-uniform loop)
        float Pc0 = 0.0f, Pc1 = 0.0f;
        #pragma unroll
        for (int j = 0; j < NWAVE - 1; j++) {
            if (j < wave) {
                const float2 a = sagg[buf][j];
                const float4 mw = sMw[f][j >> 1];
                const float n0 = fmaf(mw.x, Pc0, fmaf(mw.y, Pc1, a.x));
                const float n1 = fmaf(mw.z, Pc0, fmaf(mw.w, Pc1, a.y));
                Pc0 = n0; Pc1 = n1;
            }
        }

        // -------- wave 11: block-inclusive from own registers -> publish ----
        if (wave == NWAVE - 1 && quarter < NBLK - 1 && lane == 63) {
            const float4 mw = sMw[f][(NWAVE - 1) >> 1];
            const float i0 = fmaf(mw.x, Pc0, fmaf(mw.y, Pc1, Ac0));
            const float i1 = fmaf(mw.z, Pc0, fmaf(mw.w, Pc1, Ac1));
            unsigned int* slot = stagebase + quarter * 8;
            float* dp = (float*)(slot + 1);
            __hip_atomic_store(&dp[0], i0, __ATOMIC_RELAXED, __HIP_MEMORY_SCOPE_AGENT);
            __hip_atomic_store(&dp[1], i1, __ATOMIC_RELAXED, __HIP_MEMORY_SCOPE_AGENT);
            __hip_atomic_store(slot, tag, __ATOMIC_RELEASE, __HIP_MEMORY_SCOPE_AGENT);
        }

        // -------- block incoming state S0 (single poller: wave 0) -----------
        float S0x = 0.0f, S0y = 0.0f;
        if (quarter > 0) {
            if (wave == 0) {
                float ux = 0.0f, uy = 0.0f;
                if (lane < quarter) {
                    unsigned int* slot = stagebase + lane * 8;
                    while (__hip_atomic_load(slot, __ATOMIC_ACQUIRE, __HIP_MEMORY_SCOPE_AGENT) != tag) {
                        __builtin_amdgcn_s_sleep(1);
                    }
                    const float* dp = (const float*)(slot + 1);
                    const float cx = __hip_atomic_load(&dp[0], __ATOMIC_RELAXED, __HIP_MEMORY_SCOPE_AGENT);
                    const float cy = __hip_atomic_load(&dp[1], __ATOMIC_RELAXED, __HIP_MEMORY_SCOPE_AGENT);
                    const float4 w = sWm[f][lane];
                    ux = fmaf(w.x, cx, w.y * cy);
                    uy = fmaf(w.z, cx, w.w * cy);
                }
                S0x = __shfl(ux, 0);
                S0y = __shfl(uy, 0);
                if (quarter > 1) { S0x += __shfl(ux, 1); S0y += __shfl(uy, 1); }
                if (quarter > 2) { S0x += __shfl(ux, 2); S0y += __shfl(uy, 2); }
                if (lane == 0) {
                    sS0 = make_float2(S0x, S0y);
                    __hip_atomic_store(&sflag[f], tag, __ATOMIC_RELEASE,
                                       __HIP_MEMORY_SCOPE_WORKGROUP);
                }
            } else {
                while (__hip_atomic_load(&sflag[f], __ATOMIC_ACQUIRE,
                                         __HIP_MEMORY_SCOPE_WORKGROUP) != tag)
                    __builtin_amdgcn_s_sleep(1);
                const float2 sb = sS0;
                S0x = sb.x; S0y = sb.y;
            }
        }

        // -------- incoming wave state v = P_w * S0 + Pc_w (local compute) ---
        const float4 pm = sPm[f][wave];
        const float vx = fmaf(pm.x, S0x, fmaf(pm.y, S0y, Pc0));
        const float vy = fmaf(pm.z, S0x, fmaf(pm.w, S0y, Pc1));

        // -------- distribute: ic = M^lane * v + ce (binexp, reg squaring) ---
        float w0 = vx, w1 = vy;
        float p00 = q2.y, p01 = q2.z, p10 = q2.w, p11 = M11v;
        #pragma unroll
        for (int b = 0; b < 6; b++) {
            if (lane & (1 << b)) {
                const float nw0 = fmaf(p00, w0, p01 * w1);
                const float nw1 = fmaf(p10, w0, p11 * w1);
                w0 = nw0; w1 = nw1;
            }
            if (b < 5) {
                const float n00 = p00 * p00 + p01 * p10;
                const float n01 = p00 * p01 + p01 * p11;
                const float n10 = p10 * p00 + p11 * p10;
                const float n11 = p10 * p01 + p11 * p11;
                p00 = n00; p01 = n01; p10 = n10; p11 = n11;
            }
        }
        ic1 = w0 + ce0;
        ic2 = w1 + ce1;

        // Phase C: true run from incoming state, write outputs in place
        FOREACH_S(STEPC)
    }

    // ---------------- store (with output gain) ----------------
    {
        const float og = sgain[1][frame];
        float* base = out + (size_t)bt * S + (size_t)(quarter * NCH + t) * CHUNK;
        float4 q;
        q.x = s00*og; q.y = s01*og; q.z = s02*og; q.w = s03*og; *(float4*)(base +  0) = q;
        q.x = s04*og; q.y = s05*og; q.z = s06*og; q.w = s07*og; *(float4*)(base +  4) = q;
        q.x = s08*og; q.y = s09*og; q.z = s10*og; q.w = s11*og; *(float4*)(base +  8) = q;
        q.x = s12*og; q.y = s13*og; q.z = s14*og; q.w = s15*og; *(float4*)(base + 12) = q;
    }
}

extern "C" void kernel_launch(void* const* d_in, const int* in_sizes, int n_in,
                              void* d_out, int out_size, void* d_ws, size_t ws_size,
                              hipStream_t stream)
{
    const float* audio  = (const float*)d_in[0];
    const float* params = (const float*)d_in[1];
    float* out = (float*)d_out;
    unsigned int* ws = (unsigned int*)d_ws;
    biquad_chain_kernel<<<NBLK * NBATCH, NCH, 0, stream>>>(audio, params, out, ws);
}